// Round 8
// baseline (166.949 us; speedup 1.0000x reference)
//
#include <hip/hip_runtime.h>
#include <cmath>

#define BN 16
#define CDIM 64
#define TOT 8192
#define KNB 20
#define CN 512
#define NSTEPS 8
#define WPB 16           // walkers per block (4 waves x 4 groups)
#define BPB 32           // blocks per batch (CN / WPB)
#define WVB 128          // waves per batch (4 per block)
#define WSTRIDE 577      // per-walker LDS out-buffer stride (64*9 + 1 pad)
#define LINE 32          // uints per flag line (128B, no false sharing)
#define MAGIC 0x5A17ECE1u  // != 0xAAAAAAAA poison — phase-1 write-once slots

typedef float vf4 __attribute__((ext_vector_type(4)));

// shared contraction so pa (precompute) == walker's exact FMA tree
__device__ __forceinline__ float dot4(float a, float b, float c, float d,
                                      float wa, float wb, float wc, float wd) {
  return a * wa + b * wb + c * wc + d * wd;
}

template <int CTRL>
__device__ __forceinline__ float dpp_add(float v) {
  int o = __builtin_amdgcn_update_dpp(0, __float_as_int(v), CTRL, 0xF, 0xF, true);
  return v + __int_as_float(o);
}

// butterfly sum across the 16-lane group — pure VALU; balanced binary tree
__device__ __forceinline__ float gred16(float v) {
  v = dpp_add<0xB1>(v);   // quad_perm xor1
  v = dpp_add<0x4E>(v);   // quad_perm xor2
  v = dpp_add<0x141>(v);  // row_half_mirror (xor4)
  v = dpp_add<0x140>(v);  // row_mirror (xor8)
  return v;
}

__global__ __launch_bounds__(256, 2) void walk_kernel(
    const float* __restrict__ x, const int* __restrict__ adj, const int* __restrict__ cur,
    const float* __restrict__ agent_w, const float* __restrict__ agent_gamma,
    const float* __restrict__ agent_beta, const float* __restrict__ agent_mean,
    const float* __restrict__ agent_var, const float* __restrict__ mom_w,
    const float* __restrict__ mom_gamma, const float* __restrict__ mom_beta,
    const float* __restrict__ mom_mean, const float* __restrict__ mom_var,
    float* __restrict__ xt, float* __restrict__ pa,
    float* __restrict__ out, float* __restrict__ sbuf,
    unsigned int* __restrict__ pflag, int* __restrict__ wflag) {
  __shared__ float lds_out[WPB * WSTRIDE];  // walk-phase out buffer; aliased as tile below
  const int tid  = threadIdx.x;
  const int lane = tid & 63;
  const int wv   = tid >> 6;
  const int g    = lane >> 4;
  const int L    = lane & 15;
  const int b     = (blockIdx.x & 7) + (((blockIdx.x >> 8) & 1) << 3);
  const int chunk = (blockIdx.x >> 3) & 31;
  const int w     = wv * 4 + g;
  const int n     = chunk * WPB + w;
  const int c0    = L << 2;
  const int W     = (chunk << 2) + wv;        // wave index within batch [0,128)
  const int P0    = (W << 1) & (WVB - 1);     // producer waves: 2W, 2W+1 (mod 128)
  const int P1    = ((W << 1) + 1) & (WVB - 1);

  // ================= phase 1: transpose + pa (fused, sc1 -> MALL) =================
  {
    float (*tile)[65] = (float (*)[65])lds_out;  // 64*65*4 = 16.6 KB, aliased
#pragma unroll 1
    for (int i = 0; i < 4; ++i) {
      const int t0 = ((chunk << 2) + i) << 6;
#pragma unroll
      for (int k = 0; k < 4; ++k) {
        int fid = tid + k * 256;
        int cc = fid >> 4, qt = (fid & 15) << 2;
        float4 vv = *(const float4*)(x + ((size_t)b * CDIM + cc) * TOT + t0 + qt);
        tile[cc][qt + 0] = vv.x; tile[cc][qt + 1] = vv.y;
        tile[cc][qt + 2] = vv.z; tile[cc][qt + 3] = vv.w;
      }
      __syncthreads();
#pragma unroll
      for (int k = 0; k < 4; ++k) {
        int fid = tid + k * 256;
        int tt = fid >> 4, qc = (fid & 15) << 2;
        vf4 vv = {tile[qc + 0][tt], tile[qc + 1][tt], tile[qc + 2][tt], tile[qc + 3][tt]};
        float* dst = xt + ((size_t)b * TOT + t0 + tt) * CDIM + qc;
        asm volatile("global_store_dwordx4 %0, %1, off sc0 sc1" :: "v"(dst), "v"(vv) : "memory");
      }
      if (tid < 64) {
        const int tt = tid;
        float q[16];
#pragma unroll
        for (int l = 0; l < 16; ++l)
          q[l] = dot4(tile[4 * l][tt], tile[4 * l + 1][tt],
                      tile[4 * l + 2][tt], tile[4 * l + 3][tt],
                      agent_w[4 * l], agent_w[4 * l + 1],
                      agent_w[4 * l + 2], agent_w[4 * l + 3]);
        float sA = (q[0] + q[1]) + (q[2] + q[3]);
        float sB = (q[4] + q[5]) + (q[6] + q[7]);
        float sC = (q[8] + q[9]) + (q[10] + q[11]);
        float sD = (q[12] + q[13]) + (q[14] + q[15]);
        __hip_atomic_store(pa + (size_t)b * TOT + t0 + tt, (sA + sB) + (sC + sD),
                           __ATOMIC_RELAXED, __HIP_MEMORY_SCOPE_AGENT);
      }
      __syncthreads();
    }
    asm volatile("s_waitcnt vmcnt(0)" ::: "memory");  // all sc1 stores at MALL
    __builtin_amdgcn_s_barrier();
    if (tid == 0)
      __hip_atomic_store(pflag + ((size_t)b * BPB + chunk) * LINE, MAGIC,
                         __ATOMIC_RELAXED, __HIP_MEMORY_SCOPE_AGENT);
    if (tid < BPB) {  // wait for all 32 blocks of this batch
      const unsigned int* f = pflag + ((size_t)b * BPB + tid) * LINE;
      while (__hip_atomic_load(f, __ATOMIC_RELAXED, __HIP_MEMORY_SCOPE_AGENT) != MAGIC)
        __builtin_amdgcn_s_sleep(2);
    }
    __builtin_amdgcn_s_barrier();
    asm volatile("" ::: "memory");
  }

  // ================= phase 2: the walk (wave-granular dataflow sync) =================
  const vf4 aw2  = *(const vf4*)(agent_w + 64 + c0);
  const vf4 mw0a = *(const vf4*)(mom_w + c0);
  const vf4 mw0b = *(const vf4*)(mom_w + 64 + c0);
  const vf4 mw1a = *(const vf4*)(mom_w + 128 + c0);
  const vf4 mw1b = *(const vf4*)(mom_w + 192 + c0);
  const float amean  = agent_mean[0];
  const float abeta  = agent_beta[0];
  const float ainv   = agent_gamma[0] / sqrtf(agent_var[0] + 1e-5f);
  const float m0mean = mom_mean[0], m1mean = mom_mean[1];
  const float m0inv  = mom_gamma[0] / sqrtf(mom_var[0] + 1e-5f);
  const float m1inv  = mom_gamma[1] / sqrtf(mom_var[1] + 1e-5f);
  const float m0beta = mom_beta[0], m1beta = mom_beta[1];

  const float* xb   = xt + (size_t)b * TOT * CDIM;
  const float* pab  = pa + (size_t)b * TOT;
  const int*   adjb = adj + (size_t)b * TOT * KNB;
  float*       lout = lds_out + w * WSTRIDE;
  int*         wfb  = wflag + (size_t)b * WVB * LINE;

  int t = cur[b * CN + n];
  vf4 pf = *(const vf4*)(xb + (size_t)t * CDIM + c0);
  vf4 cf = pf;
  vf4 u  = (vf4){0.f, 0.f, 0.f, 0.f};
  float A0v = 0.f, A1v = 0.f;

  int   idx[KNB];
  vf4   nv[KNB];
  float pav[KNB];
  {
    const int4* arow = (const int4*)(adjb + (size_t)t * KNB);
    int4 q0 = arow[0], q1 = arow[1], q2 = arow[2], q3 = arow[3], q4 = arow[4];
    int tmp[KNB] = {q0.x, q0.y, q0.z, q0.w, q1.x, q1.y, q1.z, q1.w,
                    q2.x, q2.y, q2.z, q2.w, q3.x, q3.y, q3.z, q3.w,
                    q4.x, q4.y, q4.z, q4.w};
#pragma unroll
    for (int j = 0; j < KNB; ++j) idx[j] = tmp[j];
#pragma unroll
    for (int j = 0; j < KNB; ++j) {
      nv[j]  = *(const vf4*)(xb + (size_t)idx[j] * CDIM + c0);
      pav[j] = pab[idx[j]];
    }
  }

#pragma unroll 1
  for (int s = 0; s < NSTEPS; ++s) {
    float n1 = 0.f;
    if (s > 0) {
      // A0v/A1v were loaded at the bottom of step s-1 (post-poll)
      pf.x = A0v * cf.x + A1v * pf.x;
      pf.y = A0v * cf.y + A1v * pf.y;
      pf.z = A0v * cf.z + A1v * pf.z;
      pf.w = A0v * cf.w + A1v * pf.w;
      u.x = cf.x - pf.x; u.y = cf.y - pf.y; u.z = cf.z - pf.z; u.w = cf.w - pf.w;
      n1 = sqrtf(gred16(u.x * u.x + u.y * u.y + u.z * u.z + u.w * u.w));
    }
    float pw = gred16(pf.x * aw2.x + pf.y * aw2.y + pf.z * aw2.z + pf.w * aw2.w);

    float bestp = -3.4e38f;
    int   bestt = 0;
    vf4   bestv = (vf4){0.f, 0.f, 0.f, 0.f};
#pragma unroll
    for (int j = 0; j < KNB; ++j) {
      const vf4 v = nv[j];
      float logit = (pav[j] + pw - amean) * ainv + abeta;
      float p;
      if (s > 0) {
        float tx = v.x - cf.x, ty = v.y - cf.y, tz = v.z - cf.z, tw = v.w - cf.w;
        float su = tx * u.x + ty * u.y + tz * u.z + tw * u.w;
        float sn = tx * tx + ty * ty + tz * tz + tw * tw;
        su = gred16(su);
        sn = gred16(sn);
        float den  = fmaxf(n1 * sqrtf(sn), 1e-8f);
        float cosv = su * __builtin_amdgcn_rcpf(den);
        float dfac = fminf(fmaxf(1.0f + cosv, 0.0f), 1.0f);
        p = logit * dfac;
      } else {
        p = logit;
      }
      if (p > bestp) { bestp = p; bestt = idx[j]; bestv = v; }
    }
    cf = bestv;
    t  = bestt;
    lout[(c0 + 0) * 9 + s] = cf.x;
    lout[(c0 + 1) * 9 + s] = cf.y;
    lout[(c0 + 2) * 9 + s] = cf.z;
    lout[(c0 + 3) * 9 + s] = cf.w;

    if (s < NSTEPS - 1) {
      // ---- momentum logits for step s+1 ----
      float p0 = cf.x * mw0a.x + cf.y * mw0a.y + cf.z * mw0a.z + cf.w * mw0a.w +
                 pf.x * mw0b.x + pf.y * mw0b.y + pf.z * mw0b.z + pf.w * mw0b.w;
      float p1 = cf.x * mw1a.x + cf.y * mw1a.y + cf.z * mw1a.z + cf.w * mw1a.w +
                 pf.x * mw1b.x + pf.y * mw1b.y + pf.z * mw1b.z + pf.w * mw1b.w;
      p0 = gred16(p0);
      p1 = gred16(p1);
      float mlog0 = (p0 - m0mean) * m0inv + m0beta;
      float mlog1 = (p1 - m1mean) * m1inv + m1beta;
      float mx = fmaxf(mlog0, mlog1);
      float e0 = expf(mlog0 - mx), e1 = expf(mlog1 - mx);
      float sinv = 1.0f / (e0 + e1);
      float* sb = sbuf + ((size_t)(b * NSTEPS + s + 1) << 10);
      if (L == 0) {
        __hip_atomic_store(sb + n, e0 * sinv, __ATOMIC_RELAXED, __HIP_MEMORY_SCOPE_AGENT);
        __hip_atomic_store(sb + CN + n, e1 * sinv, __ATOMIC_RELAXED, __HIP_MEMORY_SCOPE_AGENT);
      }
      asm volatile("s_waitcnt vmcnt(0)" ::: "memory");  // S at coherence point
      if (lane == 0)
        __hip_atomic_store(wfb + W * LINE, s + 1, __ATOMIC_RELAXED, __HIP_MEMORY_SCOPE_AGENT);
      // ---- poll ONLY our two producer waves (dataflow, no barriers) ----
      {
        const int* f0 = wfb + P0 * LINE;
        const int* f1 = wfb + P1 * LINE;
        while (__hip_atomic_load(f0, __ATOMIC_RELAXED, __HIP_MEMORY_SCOPE_AGENT) <= s ||
               __hip_atomic_load(f1, __ATOMIC_RELAXED, __HIP_MEMORY_SCOPE_AGENT) <= s)
          __builtin_amdgcn_s_sleep(1);
      }
      asm volatile("" ::: "memory");
      // A coeffs for step s+1 — issued BEFORE the gathers so their waitcnt
      // doesn't drain the prefetch queue
      const float* sbr = sbuf + ((size_t)(b * NSTEPS + s + 1) << 10);
      A0v = __hip_atomic_load(sbr + 2 * n, __ATOMIC_RELAXED, __HIP_MEMORY_SCOPE_AGENT);
      A1v = __hip_atomic_load(sbr + 2 * n + 1, __ATOMIC_RELAXED, __HIP_MEMORY_SCOPE_AGENT);
      // ---- prefetch next neighborhood ----
      const int4* arow = (const int4*)(adjb + (size_t)t * KNB);
      int4 q0 = arow[0], q1 = arow[1], q2 = arow[2], q3 = arow[3], q4 = arow[4];
      int tmp[KNB] = {q0.x, q0.y, q0.z, q0.w, q1.x, q1.y, q1.z, q1.w,
                      q2.x, q2.y, q2.z, q2.w, q3.x, q3.y, q3.z, q3.w,
                      q4.x, q4.y, q4.z, q4.w};
#pragma unroll
      for (int j = 0; j < KNB; ++j) idx[j] = tmp[j];
#pragma unroll
      for (int j = 0; j < KNB; ++j) {
        nv[j]  = *(const vf4*)(xb + (size_t)idx[j] * CDIM + c0);
        pav[j] = pab[idx[j]];
      }
    }
  }

  // single coalesced write phase: out[b][c][n][0..7] = 32B per (c,n)
#pragma unroll
  for (int e = 0; e < 4; ++e) {
    const float* src = lout + (c0 + e) * 9;
    float4 w0 = make_float4(src[0], src[1], src[2], src[3]);
    float4 w1 = make_float4(src[4], src[5], src[6], src[7]);
    float* op = out + (((size_t)(b * CDIM + c0 + e) * CN) + n) * NSTEPS;
    *(float4*)(op)     = w0;
    *(float4*)(op + 4) = w1;
  }
}

extern "C" void kernel_launch(void* const* d_in, const int* in_sizes, int n_in,
                              void* d_out, int out_size, void* d_ws, size_t ws_size,
                              hipStream_t stream) {
  (void)in_sizes; (void)n_in; (void)out_size; (void)ws_size;
  const float* x          = (const float*)d_in[1];
  const int*   adj        = (const int*)d_in[2];
  const int*   cur        = (const int*)d_in[3];
  const float* agent_w    = (const float*)d_in[4];
  const float* agent_gamma= (const float*)d_in[5];
  const float* agent_beta = (const float*)d_in[6];
  const float* agent_mean = (const float*)d_in[7];
  const float* agent_var  = (const float*)d_in[8];
  const float* mom_w      = (const float*)d_in[9];
  const float* mom_gamma  = (const float*)d_in[10];
  const float* mom_beta   = (const float*)d_in[11];
  const float* mom_mean   = (const float*)d_in[12];
  const float* mom_var    = (const float*)d_in[13];
  float* out = (float*)d_out;

  char* ws = (char*)d_ws;
  const size_t xt_bytes   = (size_t)BN * TOT * CDIM * sizeof(float);       // 33.5 MB
  const size_t sbuf_bytes = (size_t)BN * NSTEPS * 2 * CN * sizeof(float);  // 512 KB
  const size_t pa_bytes   = (size_t)BN * TOT * sizeof(float);              // 512 KB
  const size_t pf_bytes   = (size_t)BN * BPB * LINE * sizeof(unsigned);    // 64 KB
  float*        xt    = (float*)ws;
  float*        sbuf  = (float*)(ws + xt_bytes);
  float*        pab   = (float*)(ws + xt_bytes + sbuf_bytes);
  unsigned int* pflag = (unsigned int*)(ws + xt_bytes + sbuf_bytes + pa_bytes);
  int*          wflag = (int*)(ws + xt_bytes + sbuf_bytes + pa_bytes + pf_bytes);
  // wflag: 0xAAAAAAAA poison is NEGATIVE as int -> "not yet at step s+1" without init

  walk_kernel<<<BN * BPB, 256, 0, stream>>>(x, adj, cur, agent_w, agent_gamma, agent_beta,
                                            agent_mean, agent_var, mom_w, mom_gamma, mom_beta,
                                            mom_mean, mom_var, xt, pab, out, sbuf, pflag, wflag);
}

// Round 9
// 160.974 us; speedup vs baseline: 1.0371x; 1.0371x over previous
//
#include <hip/hip_runtime.h>
#include <cmath>

#define BN 16
#define CDIM 64
#define TOT 8192
#define KNB 20
#define CN 512
#define NSTEPS 8
#define WPB 16           // walkers per block (4 waves x 4 groups)
#define BPB 32           // blocks per batch (CN / WPB)
#define WSTRIDE 577      // per-walker LDS out-buffer stride (64*9 + 1 pad)
#define LINE 32          // uints per flag line (128B, no false sharing)
#define MAGIC 0x5A17ECE1u   // phase-1 write-once slots (!= poison)
#define POISON 0xAAAAAAAAu  // harness ws poison; sign-bit 1 -> never a softmax value

typedef float vf4 __attribute__((ext_vector_type(4)));

// shared contraction so pa (precompute) == walker's exact FMA tree
__device__ __forceinline__ float dot4(float a, float b, float c, float d,
                                      float wa, float wb, float wc, float wd) {
  return a * wa + b * wb + c * wc + d * wd;
}

template <int CTRL>
__device__ __forceinline__ float dpp_add(float v) {
  int o = __builtin_amdgcn_update_dpp(0, __float_as_int(v), CTRL, 0xF, 0xF, true);
  return v + __int_as_float(o);
}

// butterfly sum across the 16-lane group — pure VALU; balanced binary tree
__device__ __forceinline__ float gred16(float v) {
  v = dpp_add<0xB1>(v);   // quad_perm xor1
  v = dpp_add<0x4E>(v);   // quad_perm xor2
  v = dpp_add<0x141>(v);  // row_half_mirror (xor4)
  v = dpp_add<0x140>(v);  // row_mirror (xor8)
  return v;
}

__global__ __launch_bounds__(256, 2) void walk_kernel(
    const float* __restrict__ x, const int* __restrict__ adj, const int* __restrict__ cur,
    const float* __restrict__ agent_w, const float* __restrict__ agent_gamma,
    const float* __restrict__ agent_beta, const float* __restrict__ agent_mean,
    const float* __restrict__ agent_var, const float* __restrict__ mom_w,
    const float* __restrict__ mom_gamma, const float* __restrict__ mom_beta,
    const float* __restrict__ mom_mean, const float* __restrict__ mom_var,
    float* __restrict__ xt, float* __restrict__ pa,
    float* __restrict__ out, float* __restrict__ sbuf,
    unsigned int* __restrict__ pflag) {
  __shared__ float lds_out[WPB * WSTRIDE];  // walk-phase out buffer; aliased as tile below
  const int tid  = threadIdx.x;
  const int lane = tid & 63;
  const int wv   = tid >> 6;
  const int g    = lane >> 4;
  const int L    = lane & 15;
  const int b     = (blockIdx.x & 7) + (((blockIdx.x >> 8) & 1) << 3);
  const int chunk = (blockIdx.x >> 3) & 31;
  const int w     = wv * 4 + g;
  const int n     = chunk * WPB + w;
  const int c0    = L << 2;
  // consumer word offsets for the momentum-coeff scramble (data-is-flag):
  // word[2m]=S0[m], word[2m+1]=S1[m]; A0=word[(4n&1023)+off], A1=+2  (off = n>=256)
  const int mbase = (n << 2) & 1023;
  const int moff  = (n >= 256) ? 1 : 0;

  // ================= phase 1: transpose + pa (fused, sc1 -> MALL) =================
  {
    float (*tile)[65] = (float (*)[65])lds_out;  // 64*65*4 = 16.6 KB, aliased
#pragma unroll 1
    for (int i = 0; i < 4; ++i) {
      const int t0 = ((chunk << 2) + i) << 6;
#pragma unroll
      for (int k = 0; k < 4; ++k) {
        int fid = tid + k * 256;
        int cc = fid >> 4, qt = (fid & 15) << 2;
        float4 vv = *(const float4*)(x + ((size_t)b * CDIM + cc) * TOT + t0 + qt);
        tile[cc][qt + 0] = vv.x; tile[cc][qt + 1] = vv.y;
        tile[cc][qt + 2] = vv.z; tile[cc][qt + 3] = vv.w;
      }
      __syncthreads();
#pragma unroll
      for (int k = 0; k < 4; ++k) {
        int fid = tid + k * 256;
        int tt = fid >> 4, qc = (fid & 15) << 2;
        vf4 vv = {tile[qc + 0][tt], tile[qc + 1][tt], tile[qc + 2][tt], tile[qc + 3][tt]};
        float* dst = xt + ((size_t)b * TOT + t0 + tt) * CDIM + qc;
        asm volatile("global_store_dwordx4 %0, %1, off sc0 sc1" :: "v"(dst), "v"(vv) : "memory");
      }
      if (tid < 64) {
        const int tt = tid;
        float q[16];
#pragma unroll
        for (int l = 0; l < 16; ++l)
          q[l] = dot4(tile[4 * l][tt], tile[4 * l + 1][tt],
                      tile[4 * l + 2][tt], tile[4 * l + 3][tt],
                      agent_w[4 * l], agent_w[4 * l + 1],
                      agent_w[4 * l + 2], agent_w[4 * l + 3]);
        float sA = (q[0] + q[1]) + (q[2] + q[3]);
        float sB = (q[4] + q[5]) + (q[6] + q[7]);
        float sC = (q[8] + q[9]) + (q[10] + q[11]);
        float sD = (q[12] + q[13]) + (q[14] + q[15]);
        __hip_atomic_store(pa + (size_t)b * TOT + t0 + tt, (sA + sB) + (sC + sD),
                           __ATOMIC_RELAXED, __HIP_MEMORY_SCOPE_AGENT);
      }
      __syncthreads();
    }
    asm volatile("s_waitcnt vmcnt(0)" ::: "memory");  // all sc1 stores at MALL
    __builtin_amdgcn_s_barrier();
    if (tid == 0)
      __hip_atomic_store(pflag + ((size_t)b * BPB + chunk) * LINE, MAGIC,
                         __ATOMIC_RELAXED, __HIP_MEMORY_SCOPE_AGENT);
    if (tid < BPB) {  // wait for all 32 blocks of this batch
      const unsigned int* f = pflag + ((size_t)b * BPB + tid) * LINE;
      while (__hip_atomic_load(f, __ATOMIC_RELAXED, __HIP_MEMORY_SCOPE_AGENT) != MAGIC)
        __builtin_amdgcn_s_sleep(2);
    }
    __builtin_amdgcn_s_barrier();
    asm volatile("" ::: "memory");
  }

  // ================= phase 2: the walk (data-is-flag sync) =================
  const vf4 aw2  = *(const vf4*)(agent_w + 64 + c0);
  const vf4 mw0a = *(const vf4*)(mom_w + c0);
  const vf4 mw0b = *(const vf4*)(mom_w + 64 + c0);
  const vf4 mw1a = *(const vf4*)(mom_w + 128 + c0);
  const vf4 mw1b = *(const vf4*)(mom_w + 192 + c0);
  const float amean  = agent_mean[0];
  const float abeta  = agent_beta[0];
  const float ainv   = agent_gamma[0] / sqrtf(agent_var[0] + 1e-5f);
  const float m0mean = mom_mean[0], m1mean = mom_mean[1];
  const float m0inv  = mom_gamma[0] / sqrtf(mom_var[0] + 1e-5f);
  const float m1inv  = mom_gamma[1] / sqrtf(mom_var[1] + 1e-5f);
  const float m0beta = mom_beta[0], m1beta = mom_beta[1];

  const float* xb   = xt + (size_t)b * TOT * CDIM;
  const float* pab  = pa + (size_t)b * TOT;
  const int*   adjb = adj + (size_t)b * TOT * KNB;
  float*       lout = lds_out + w * WSTRIDE;

  int t = cur[b * CN + n];
  vf4 pf = *(const vf4*)(xb + (size_t)t * CDIM + c0);
  vf4 cf = pf;
  vf4 u  = (vf4){0.f, 0.f, 0.f, 0.f};
  float A0v = 0.f, A1v = 0.f;

  int   idx[KNB];
  vf4   nv[KNB];
  float pav[KNB];
  float sq[KNB];
  {
    const int4* arow = (const int4*)(adjb + (size_t)t * KNB);
    int4 q0 = arow[0], q1 = arow[1], q2 = arow[2], q3 = arow[3], q4 = arow[4];
    int tmp[KNB] = {q0.x, q0.y, q0.z, q0.w, q1.x, q1.y, q1.z, q1.w,
                    q2.x, q2.y, q2.z, q2.w, q3.x, q3.y, q3.z, q3.w,
                    q4.x, q4.y, q4.z, q4.w};
#pragma unroll
    for (int j = 0; j < KNB; ++j) idx[j] = tmp[j];
#pragma unroll
    for (int j = 0; j < KNB; ++j) {
      nv[j]  = *(const vf4*)(xb + (size_t)idx[j] * CDIM + c0);
      pav[j] = pab[idx[j]];
    }
  }

#pragma unroll 1
  for (int s = 0; s < NSTEPS; ++s) {
    float n1 = 0.f;
    if (s > 0) {
      // A0v/A1v came from the data-poll at the bottom of step s-1
      pf.x = A0v * cf.x + A1v * pf.x;
      pf.y = A0v * cf.y + A1v * pf.y;
      pf.z = A0v * cf.z + A1v * pf.z;
      pf.w = A0v * cf.w + A1v * pf.w;
      u.x = cf.x - pf.x; u.y = cf.y - pf.y; u.z = cf.z - pf.z; u.w = cf.w - pf.w;
      n1 = sqrtf(gred16(u.x * u.x + u.y * u.y + u.z * u.z + u.w * u.w));
    }
    float pw = gred16(pf.x * aw2.x + pf.y * aw2.y + pf.z * aw2.z + pf.w * aw2.w);

    float bestp = -3.4e38f;
    int   bestt = 0;
    vf4   bestv = (vf4){0.f, 0.f, 0.f, 0.f};
#pragma unroll
    for (int j = 0; j < KNB; ++j) {
      const vf4 v = nv[j];
      float logit = (pav[j] + pw - amean) * ainv + abeta;
      float p;
      if (s > 0) {
        float tx = v.x - cf.x, ty = v.y - cf.y, tz = v.z - cf.z, tw = v.w - cf.w;
        float su = tx * u.x + ty * u.y + tz * u.z + tw * u.w;
        su = gred16(su);
        float den  = fmaxf(n1 * sq[j], 1e-8f);    // sq[j]=sqrtf(gred16(sn)) precomputed
        float cosv = su * __builtin_amdgcn_rcpf(den);
        float dfac = fminf(fmaxf(1.0f + cosv, 0.0f), 1.0f);
        p = logit * dfac;
      } else {
        p = logit;
      }
      if (p > bestp) { bestp = p; bestt = idx[j]; bestv = v; }
    }
    cf = bestv;
    t  = bestt;
    lout[(c0 + 0) * 9 + s] = cf.x;
    lout[(c0 + 1) * 9 + s] = cf.y;
    lout[(c0 + 2) * 9 + s] = cf.z;
    lout[(c0 + 3) * 9 + s] = cf.w;

    if (s < NSTEPS - 1) {
      // ---- momentum logits for step s+1; publish (S0,S1) as ONE packed 8-B
      //      relaxed store. Data IS the flag (poison-sentinel) -> NO drain. ----
      float p0 = cf.x * mw0a.x + cf.y * mw0a.y + cf.z * mw0a.z + cf.w * mw0a.w +
                 pf.x * mw0b.x + pf.y * mw0b.y + pf.z * mw0b.z + pf.w * mw0b.w;
      float p1 = cf.x * mw1a.x + cf.y * mw1a.y + cf.z * mw1a.z + cf.w * mw1a.w +
                 pf.x * mw1b.x + pf.y * mw1b.y + pf.z * mw1b.z + pf.w * mw1b.w;
      p0 = gred16(p0);
      p1 = gred16(p1);
      float mlog0 = (p0 - m0mean) * m0inv + m0beta;
      float mlog1 = (p1 - m1mean) * m1inv + m1beta;
      float mx = fmaxf(mlog0, mlog1);
      float e0 = expf(mlog0 - mx), e1 = expf(mlog1 - mx);
      float sinv = 1.0f / (e0 + e1);
      float* sb = sbuf + ((size_t)(b * NSTEPS + s + 1) << 10);
      if (L == 0) {
        unsigned long long pk =
            (unsigned long long)__float_as_uint(e0 * sinv) |
            ((unsigned long long)__float_as_uint(e1 * sinv) << 32);
        __hip_atomic_store((unsigned long long*)sb + n, pk,
                           __ATOMIC_RELAXED, __HIP_MEMORY_SCOPE_AGENT);
      }
      // ---- prefetch next neighborhood BEFORE the poll (t-dependent only) ----
      const int4* arow = (const int4*)(adjb + (size_t)t * KNB);
      int4 q0 = arow[0], q1 = arow[1], q2 = arow[2], q3 = arow[3], q4 = arow[4];
      int tmp[KNB] = {q0.x, q0.y, q0.z, q0.w, q1.x, q1.y, q1.z, q1.w,
                      q2.x, q2.y, q2.z, q2.w, q3.x, q3.y, q3.z, q3.w,
                      q4.x, q4.y, q4.z, q4.w};
#pragma unroll
      for (int j = 0; j < KNB; ++j) idx[j] = tmp[j];
#pragma unroll
      for (int j = 0; j < KNB; ++j) {
        nv[j]  = *(const vf4*)(xb + (size_t)idx[j] * CDIM + c0);
        pav[j] = pab[idx[j]];
      }
      // ---- pf-independent cosine prefix in the poll shadow (bitwise-same) ----
#pragma unroll
      for (int j = 0; j < KNB; ++j) {
        const vf4 v = nv[j];
        float tx = v.x - cf.x, ty = v.y - cf.y, tz = v.z - cf.z, tw = v.w - cf.w;
        float sn = tx * tx + ty * ty + tz * tz + tw * tw;
        sq[j] = sqrtf(gred16(sn));
      }
      // ---- poll the producer S words directly (one MALL round trip) ----
      {
        const unsigned* sbw = (const unsigned*)sb;
        const unsigned* q0p = sbw + mbase + moff;
        const unsigned* q2p = q0p + 2;
        unsigned w0, w2;
        for (;;) {
          w0 = __hip_atomic_load(q0p, __ATOMIC_RELAXED, __HIP_MEMORY_SCOPE_AGENT);
          w2 = __hip_atomic_load(q2p, __ATOMIC_RELAXED, __HIP_MEMORY_SCOPE_AGENT);
          if (w0 != POISON && w2 != POISON) break;
          __builtin_amdgcn_s_sleep(1);
        }
        A0v = __uint_as_float(w0);
        A1v = __uint_as_float(w2);
      }
      asm volatile("" ::: "memory");
    }
  }

  // single coalesced write phase: out[b][c][n][0..7] = 32B per (c,n)
#pragma unroll
  for (int e = 0; e < 4; ++e) {
    const float* src = lout + (c0 + e) * 9;
    float4 w0 = make_float4(src[0], src[1], src[2], src[3]);
    float4 w1 = make_float4(src[4], src[5], src[6], src[7]);
    float* op = out + (((size_t)(b * CDIM + c0 + e) * CN) + n) * NSTEPS;
    *(float4*)(op)     = w0;
    *(float4*)(op + 4) = w1;
  }
}

extern "C" void kernel_launch(void* const* d_in, const int* in_sizes, int n_in,
                              void* d_out, int out_size, void* d_ws, size_t ws_size,
                              hipStream_t stream) {
  (void)in_sizes; (void)n_in; (void)out_size; (void)ws_size;
  const float* x          = (const float*)d_in[1];
  const int*   adj        = (const int*)d_in[2];
  const int*   cur        = (const int*)d_in[3];
  const float* agent_w    = (const float*)d_in[4];
  const float* agent_gamma= (const float*)d_in[5];
  const float* agent_beta = (const float*)d_in[6];
  const float* agent_mean = (const float*)d_in[7];
  const float* agent_var  = (const float*)d_in[8];
  const float* mom_w      = (const float*)d_in[9];
  const float* mom_gamma  = (const float*)d_in[10];
  const float* mom_beta   = (const float*)d_in[11];
  const float* mom_mean   = (const float*)d_in[12];
  const float* mom_var    = (const float*)d_in[13];
  float* out = (float*)d_out;

  char* ws = (char*)d_ws;
  const size_t xt_bytes   = (size_t)BN * TOT * CDIM * sizeof(float);       // 33.5 MB
  const size_t sbuf_bytes = (size_t)BN * NSTEPS * 2 * CN * sizeof(float);  // 512 KB
  const size_t pa_bytes   = (size_t)BN * TOT * sizeof(float);              // 512 KB
  float*        xt    = (float*)ws;
  float*        sbuf  = (float*)(ws + xt_bytes);   // per-step S pairs; poison = sentinel
  float*        pab   = (float*)(ws + xt_bytes + sbuf_bytes);
  unsigned int* pflag = (unsigned int*)(ws + xt_bytes + sbuf_bytes + pa_bytes);

  walk_kernel<<<BN * BPB, 256, 0, stream>>>(x, adj, cur, agent_w, agent_gamma, agent_beta,
                                            agent_mean, agent_var, mom_w, mom_gamma, mom_beta,
                                            mom_mean, mom_var, xt, pab, out, sbuf, pflag);
}